// Round 1
// baseline (707.701 us; speedup 1.0000x reference)
//
#include <hip/hip_runtime.h>

#define CUT 32

// W2[n][m] = (re, im) of kerr[m] * G[m][n], interleaved. 8 KiB.
__device__ __align__(16) float g_W2[CUT * CUT * 2];

// ---------------------------------------------------------------------------
// Kernel A: build the Gaussian-unitary matrix (with Kerr folded in) in fp64.
// One wave. Lane m (m < 32) owns row m of the current column.
// ---------------------------------------------------------------------------
__global__ __launch_bounds__(64) void build_W(
    const float* __restrict__ gre, const float* __restrict__ gim,
    const float* __restrict__ phi_p, const float* __restrict__ zre,
    const float* __restrict__ zim, const float* __restrict__ kap)
{
    const int lane = threadIdx.x;

    const double gr = (double)gre[0], gi = (double)gim[0];
    const double ph = (double)phi_p[0];
    const double zr = (double)zre[0], zi = (double)zim[0];
    const double kp = (double)kap[0];

    const double r     = sqrt(zr * zr + zi * zi);
    const double delta = atan2(zi, zr);
    const double T     = tanh(r);
    const double sech  = 1.0 / cosh(r);

    const double adp = delta + 2.0 * ph;
    const double edr = cos(adp), edi = sin(adp);   // e^{i(delta+2phi)}

    // g00 = exp(-0.5*(|g|^2 + conj(g)^2 * eidp * T)) * sqrt(sech)
    const double cg2r = gr * gr - gi * gi, cg2i = -2.0 * gr * gi;
    const double wr_  = (cg2r * edr - cg2i * edi) * T;
    const double wi_  = (cg2r * edi + cg2i * edr) * T;
    const double exr  = -0.5 * (gr * gr + gi * gi + wr_);
    const double exi  = -0.5 * wi_;
    const double mag  = exp(exr) * sqrt(sech);
    const double g00r = mag * cos(exi), g00i = mag * sin(exi);

    // A = gamma + conj(gamma)*eidp*T ; B = eidp*T
    const double cgTr = (gr * edr + gi * edi) * T;
    const double cgTi = (gr * edi - gi * edr) * T;
    const double Ar = gr + cgTr, Ai = gi + cgTi;
    const double Br = edr * T,   Bi = edi * T;

    // per-lane sqrt tables (extracted with __shfl during the serial loops)
    const double dl  = (double)lane;
    const double sq  = sqrt(dl);                       // sqrt(lane)
    const double isq = (lane > 0) ? 1.0 / sq : 0.0;    // 1/sqrt(lane)

    // ---- column 0: serial three-term recurrence in m (uniform values) ----
    double cr = (lane == 0) ? g00r : 0.0;
    double ci = (lane == 0) ? g00i : 0.0;
    double g1r = g00r, g1i = g00i, g2r = 0.0, g2i = 0.0;
    for (int m = 1; m < CUT; ++m) {
        const double sm1 = __shfl(sq, m - 1);
        const double ism = __shfl(isq, m);
        double tr = Ar * g1r - Ai * g1i - sm1 * (Br * g2r - Bi * g2i);
        double ti = Ar * g1i + Ai * g1r - sm1 * (Br * g2i + Bi * g2r);
        tr *= ism; ti *= ism;
        if (lane == m) { cr = tr; ci = ti; }
        g2r = g1r; g2i = g1i; g1r = tr; g1i = ti;
    }

    const double Pr = cos(ph) * sech,  Pi = sin(ph) * sech;   // e^{i phi} sech
    const double Qr = cos(delta) * T,  Qi = -sin(delta) * T;  // e^{-i delta} tanh
    const double gbr = gr, gbi = -gi;                         // conj(gamma)

    // Kerr factor for row m = lane: e^{i kappa m^2}
    const double ka = kp * dl * dl;
    const double kr = cos(ka), ki = sin(ka);

    if (lane < CUT) {
        g_W2[(0 * CUT + lane) * 2 + 0] = (float)(kr * cr - ki * ci);
        g_W2[(0 * CUT + lane) * 2 + 1] = (float)(kr * ci + ki * cr);
    }

    // ---- columns n -> n+1: parallel in m, shift via shfl_up ----
    double pr = 0.0, pi = 0.0;
    for (int n = 0; n < CUT - 1; ++n) {
        double upr = __shfl_up(cr, 1);
        double upi = __shfl_up(ci, 1);
        if (lane == 0) { upr = 0.0; upi = 0.0; }
        const double sn   = __shfl(sq, n);
        const double isn1 = __shfl(isq, n + 1);
        // t = sqrt(m)*c[m-1] - conj(gamma)*c[m]
        const double tr = sq * upr - (gbr * cr - gbi * ci);
        const double ti = sq * upi - (gbr * ci + gbi * cr);
        // u = (P*t + Q*sqrt(n)*c_prev) / sqrt(n+1)
        double ur = (Pr * tr - Pi * ti + sn * (Qr * pr - Qi * pi)) * isn1;
        double ui = (Pr * ti + Pi * tr + sn * (Qr * pi + Qi * pr)) * isn1;
        if (lane < CUT) {
            g_W2[((n + 1) * CUT + lane) * 2 + 0] = (float)(kr * ur - ki * ui);
            g_W2[((n + 1) * CUT + lane) * 2 + 1] = (float)(kr * ui + ki * ur);
        }
        pr = cr; pi = ci; cr = ur; ci = ui;
    }
}

// ---------------------------------------------------------------------------
// Kernel B: out[b,m] = sum_n W[m,n] * state[b,n], ONE row per thread.
// Key change vs previous version: each state row is exactly one 128 B cache
// line; load the whole line up front (8x float4 per array) so HBM sees each
// line exactly once. Previous 16B-per-iteration pattern re-fetched each line
// ~4x from HBM (FETCH_SIZE 990 MB vs 268 MB ideal).
// ---------------------------------------------------------------------------
__global__ __launch_bounds__(256, 3) void apply_W(
    const float* __restrict__ sre, const float* __restrict__ sim,
    float* __restrict__ out, int batch)
{
    __shared__ __align__(16) float W[CUT * CUT * 2];
    const int t = threadIdx.x;
    {
        const float4* src = (const float4*)g_W2;
        float4* dst = (float4*)W;
        dst[t]       = src[t];
        dst[t + 256] = src[t + 256];
    }
    __syncthreads();

    const long r = (long)blockIdx.x * 256 + t;
    if (r >= batch) return;

    const float4* sre4 = (const float4*)sre + r * 8;
    const float4* sim4 = (const float4*)sim + r * 8;

    // Load the full row (two 128B lines: re + im) into registers, back-to-back.
    float4 vre[8], vim[8];
    #pragma unroll
    for (int c = 0; c < 8; ++c) {
        vre[c] = sre4[c];
        vim[c] = sim4[c];
    }

    float ar[CUT], ai[CUT];
    #pragma unroll
    for (int m = 0; m < CUT; ++m) { ar[m] = 0.f; ai[m] = 0.f; }

    // Fully unrolled so all vre/vim indices are static (no scratch).
    #pragma unroll
    for (int c = 0; c < 8; ++c) {
        const float srv[4] = {vre[c].x, vre[c].y, vre[c].z, vre[c].w};
        const float siv[4] = {vim[c].x, vim[c].y, vim[c].z, vim[c].w};
        #pragma unroll
        for (int j = 0; j < 4; ++j) {
            const float sr = srv[j], si = siv[j];
            const float* Wn = &W[(c * 4 + j) * (2 * CUT)];
            #pragma unroll
            for (int m2 = 0; m2 < 16; ++m2) {
                const float4 wv = *(const float4*)&Wn[4 * m2]; // (wr,wi) x2
                const int m = 2 * m2;
                ar[m]     = fmaf(wv.x, sr, fmaf(-wv.y, si, ar[m]));
                ai[m]     = fmaf(wv.x, si, fmaf( wv.y, sr, ai[m]));
                ar[m + 1] = fmaf(wv.z, sr, fmaf(-wv.w, si, ar[m + 1]));
                ai[m + 1] = fmaf(wv.z, si, fmaf( wv.w, sr, ai[m + 1]));
            }
        }
    }

    float4* o4 = (float4*)out + r * 16;
    #pragma unroll
    for (int m2 = 0; m2 < 16; ++m2) {
        o4[m2] = make_float4(ar[2 * m2],     ai[2 * m2],
                             ar[2 * m2 + 1], ai[2 * m2 + 1]);
    }
}

extern "C" void kernel_launch(void* const* d_in, const int* in_sizes, int n_in,
                              void* d_out, int out_size, void* d_ws, size_t ws_size,
                              hipStream_t stream) {
    const float* sre = (const float*)d_in[0];
    const float* sim = (const float*)d_in[1];
    const int batch = in_sizes[0] / CUT;

    build_W<<<1, 64, 0, stream>>>((const float*)d_in[2], (const float*)d_in[3],
                                  (const float*)d_in[4], (const float*)d_in[5],
                                  (const float*)d_in[6], (const float*)d_in[7]);

    const int blocks = (batch + 255) / 256;
    apply_W<<<blocks, 256, 0, stream>>>(sre, sim, (float*)d_out, batch);
}